// Round 13
// baseline (3208.869 us; speedup 1.0000x reference)
//
#include <hip/hip_runtime.h>

#define SEQ 2048
#define D 128

// ---------------------------------------------------------------------------
// Kernel 1: per-step J-independent quantities (fully parallel), UNNORMALIZED:
//   alpha_i  = k_s . q_i      (i <= s)
//   kqq[s]   = sum alpha_i^2          = l * (k^T Sqq_l k)
//   sl[s]    = sum alpha_i (v_s.v_i)  = l * (k^T Sqv_l v)
//   vv[s]    = v_s . v_s
//   U[s][c]  = sum_i q_i[c] alpha_i   = l * (Sqq_l k)[c]
//   invl[s]  = 1.0 / l   (fp64, for cost rescale)
// Adjacency scalars (for the scan's lagged-matvec corrections):
//   kq_adj[s] = k_{s-1} . q_s ; vv_adj[s] = v_s . v_{s-1} ; kU_adj[s] = k_{s-1} . U_s
// ---------------------------------------------------------------------------
__global__ __launch_bounds__(256) void precompute_kernel(
    const float* __restrict__ q, const float* __restrict__ k, const float* __restrict__ v,
    float* __restrict__ U, float* __restrict__ sl, float* __restrict__ kqq,
    float* __restrict__ vv, float* __restrict__ kq_adj, float* __restrict__ vv_adj,
    float* __restrict__ kU_adj, double* __restrict__ invl)
{
    const int s = blockIdx.x;
    const int tid = threadIdx.x;

    __shared__ float ks[D];
    __shared__ float vs[D];
    __shared__ float alpha[SEQ];
    __shared__ float red[8];
    __shared__ float upart[256];

    if (tid < D) ks[tid] = k[s * D + tid];
    else if (tid < 2 * D) vs[tid - D] = v[s * D + (tid - D)];
    __syncthreads();

    float p_a2 = 0.f, p_ab = 0.f;
    for (int i = tid; i <= s; i += 256) {
        const float4* qr = (const float4*)(q + (size_t)i * D);
        const float4* vr = (const float4*)(v + (size_t)i * D);
        float a = 0.f, b = 0.f;
#pragma unroll
        for (int j = 0; j < D / 4; ++j) {
            float4 q4 = qr[j];
            float4 v4 = vr[j];
            a += q4.x * ks[4 * j + 0] + q4.y * ks[4 * j + 1] + q4.z * ks[4 * j + 2] + q4.w * ks[4 * j + 3];
            b += v4.x * vs[4 * j + 0] + v4.y * vs[4 * j + 1] + v4.z * vs[4 * j + 2] + v4.w * vs[4 * j + 3];
        }
        alpha[i] = a;
        p_a2 += a * a;
        p_ab += a * b;
        if (i == s) vv[s] = b;  // v_s . v_s
    }
#pragma unroll
    for (int off = 1; off < 64; off <<= 1) {
        p_a2 += __shfl_xor(p_a2, off);
        p_ab += __shfl_xor(p_ab, off);
    }
    const int wid = tid >> 6;
    if ((tid & 63) == 0) { red[wid] = p_a2; red[4 + wid] = p_ab; }
    __syncthreads();  // also makes alpha[] visible to everyone
    if (tid == 0) {
        kqq[s] = red[0] + red[1] + red[2] + red[3];
        sl[s]  = red[4] + red[5] + red[6] + red[7];
        invl[s] = 1.0 / (double)(s + 1);
    }

    // ---- adjacency dots: wave 0 -> kq_adj[s+1], wave 1 -> vv_adj[s] ----
    if (tid < 64) {
        if (s + 1 < SEQ) {
            float p2 = ks[tid] * q[(size_t)(s + 1) * D + tid]
                     + ks[tid + 64] * q[(size_t)(s + 1) * D + 64 + tid];
#pragma unroll
            for (int off = 1; off < 64; off <<= 1) p2 += __shfl_xor(p2, off);
            if (tid == 0) kq_adj[s + 1] = p2;
        }
        if (s == 0 && tid == 0) { kq_adj[0] = 0.f; kU_adj[0] = 0.f; vv_adj[0] = 0.f; }
    } else if (tid < 128 && s > 0) {
        const int t2 = tid - 64;
        float p2 = vs[t2] * v[(size_t)(s - 1) * D + t2]
                 + vs[t2 + 64] * v[(size_t)(s - 1) * D + 64 + t2];
#pragma unroll
        for (int off = 1; off < 64; off <<= 1) p2 += __shfl_xor(p2, off);
        if (t2 == 0) vv_adj[s] = p2;
    }

    // pass 2: U[s][c] = sum_i q[i][c] * alpha[i], i parity-split over h,
    // 4 independent accumulators to break the dependent fma chain
    const int c = tid & (D - 1);
    const int h = tid >> 7;  // 0 or 1
    float a0 = 0.f, a1 = 0.f, a2 = 0.f, a3 = 0.f;
    int i = h;
    for (; i + 6 <= s; i += 8) {
        a0 = fmaf(q[(size_t)(i    ) * D + c], alpha[i    ], a0);
        a1 = fmaf(q[(size_t)(i + 2) * D + c], alpha[i + 2], a1);
        a2 = fmaf(q[(size_t)(i + 4) * D + c], alpha[i + 4], a2);
        a3 = fmaf(q[(size_t)(i + 6) * D + c], alpha[i + 6], a3);
    }
    for (; i <= s; i += 2) a0 = fmaf(q[(size_t)i * D + c], alpha[i], a0);
    upart[tid] = (a0 + a1) + (a2 + a3);
    __syncthreads();

    // U store + kU_adj[s] = k_{s-1}.U_s
    float kup = 0.f;
    if (tid < D) {
        const float uv = upart[tid] + upart[tid + D];
        U[(size_t)s * D + tid] = uv;
        if (s > 0) kup = uv * k[(size_t)(s - 1) * D + tid];
    }
#pragma unroll
    for (int off = 1; off < 64; off <<= 1) kup += __shfl_xor(kup, off);
    if (tid == 0)  red[0] = kup;
    if (tid == 64) red[1] = kup;
    __syncthreads();
    if (s > 0 && tid == 0) kU_adj[s] = red[0] + red[1];
}

// ---------------------------------------------------------------------------
// DPP helpers (R7/R10/R11-verified):
// ---------------------------------------------------------------------------
#define DPP_ADD(x, ctrl) \
    ((x) + __int_as_float(__builtin_amdgcn_update_dpp(0, __float_as_int(x), (ctrl), 0xf, 0xf, true)))
#define COMBINE8(x) do { x = DPP_ADD(x, 0xB1); x = DPP_ADD(x, 0x4E); x = DPP_ADD(x, 0x141); } while (0)
#define TAIL3(x)    do { x = DPP_ADD(x, 0x140); x = DPP_ADD(x, 0x142); x = DPP_ADD(x, 0x143); } while (0)
#define REDUCE16(x) do { x = DPP_ADD(x, 0xB1); x = DPP_ADD(x, 0x4E); x = DPP_ADD(x, 0x141); \
                         x = DPP_ADD(x, 0x140); } while (0)

#define UPDATE_J(MODE, WF, WI)                                                            \
    if ((MODE) == 2) {                                                                    \
        jr0.x = vcur*kk0.x; jr0.y = vcur*kk0.y; jr0.z = vcur*kk0.z; jr0.w = vcur*kk0.w;   \
        jr1.x = vcur*kk1.x; jr1.y = vcur*kk1.y; jr1.z = vcur*kk1.z; jr1.w = vcur*kk1.w;   \
        jr2.x = vcur*kk2.x; jr2.y = vcur*kk2.y; jr2.z = vcur*kk2.z; jr2.w = vcur*kk2.w;   \
        jr3.x = vcur*kk3.x; jr3.y = vcur*kk3.y; jr3.z = vcur*kk3.z; jr3.w = vcur*kk3.w;   \
    } else if ((MODE) == 1) {                                                             \
        const float wvr = (WI) * vcur;                                                    \
        jr0.x = fmaf(jr0.x, (WF), wvr*kk0.x); jr0.y = fmaf(jr0.y, (WF), wvr*kk0.y);       \
        jr0.z = fmaf(jr0.z, (WF), wvr*kk0.z); jr0.w = fmaf(jr0.w, (WF), wvr*kk0.w);       \
        jr1.x = fmaf(jr1.x, (WF), wvr*kk1.x); jr1.y = fmaf(jr1.y, (WF), wvr*kk1.y);       \
        jr1.z = fmaf(jr1.z, (WF), wvr*kk1.z); jr1.w = fmaf(jr1.w, (WF), wvr*kk1.w);       \
        jr2.x = fmaf(jr2.x, (WF), wvr*kk2.x); jr2.y = fmaf(jr2.y, (WF), wvr*kk2.y);       \
        jr2.z = fmaf(jr2.z, (WF), wvr*kk2.z); jr2.w = fmaf(jr2.w, (WF), wvr*kk2.w);       \
        jr3.x = fmaf(jr3.x, (WF), wvr*kk3.x); jr3.y = fmaf(jr3.y, (WF), wvr*kk3.y);       \
        jr3.z = fmaf(jr3.z, (WF), wvr*kk3.z); jr3.w = fmaf(jr3.w, (WF), wvr*kk3.w);       \
    }

// ---------------------------------------------------------------------------
// Kernel 2: sequential scan, 1024 threads (16 waves, 4/SIMD).
// ROUND-13 = R11 exactly (R12's deeper pipelines reverted — they regressed)
// MINUS one-third of the LDS traffic:
//   DS-BW model: R11 issued 192 ds_read_b128/step (16 waves x 12) at ~10-12
//   cyc DS-pipe throughput each ~= 2300 cyc/step — matches the observed
//   ~2550. k_i is only consumed POST-barrier (J-update), so it needs no LDS
//   staging: each thread now loads its 4 float4 of row k_i DIRECTLY from
//   global (L2-resident, ~200 cyc, covered by dot+reduce+barrier), issued
//   where the ring-k reads were. Ring shrinks to q,u (stagers: waves 6-9);
//   DS reads drop to 128 b128/step.
// ---------------------------------------------------------------------------
__global__ __launch_bounds__(1024, 4) void scan_kernel(
    const float* __restrict__ q, const float* __restrict__ k, const float* __restrict__ v,
    const float* __restrict__ U, const float* __restrict__ sl_arr,
    const float* __restrict__ kqq_arr, const float* __restrict__ vv_arr,
    const float* __restrict__ kq_adj, const float* __restrict__ vv_adj,
    const float* __restrict__ kU_adj, const double* __restrict__ invl_arr,
    float* __restrict__ out)  // [0,2048) costs | [2048,4096) updated | [4096,...) J
{
    const int tid  = threadIdx.x;
    const int lane = tid & 63;
    const int w    = __builtin_amdgcn_readfirstlane(tid >> 6);  // 0..15
    const int r    = tid >> 3;        // my row 0..127
    const int cg   = tid & 7;
    const int c0s  = cg * 20;         // swizzled LDS chunk offset

    float4 jr0 = make_float4(0.f, 0.f, 0.f, 0.f);
    float4 jr1 = jr0, jr2 = jr0, jr3 = jr0;

    __shared__ float ring[3][2][160];                 // [phase][q,u][swizzled]
    __shared__ __align__(16) float wred[2][16][4];    // [parity][wave][r1,r2,r3,r4]
    __shared__ __align__(16) float decLDS[2][4];      // [parity][wf,wi,mode,-]

    // stagers: waves 6..9 (tid 384..639) — q and u only; wave0 staging-free
    const bool stager = (tid >= 384) && (tid < 640);
    const int  which  = (tid >> 7) - 3;    // 0:q 1:u (when stager)
    const int  sidx   = tid & 127;
    const int  widx   = ((sidx >> 4) * 20) + (sidx & 15);  // swizzled write idx

    // ---- prologue: stage phases 0,1; gstage holds phase-2 data ----
    // invariant: phase j holds q_{j+1}, u_{j+1}
    float gstage = 0.f;
    if (stager) {
        if (which == 0) {
            ring[0][0][widx] = q[(size_t)1 * D + sidx];
            ring[1][0][widx] = q[(size_t)2 * D + sidx];
            gstage = q[(size_t)3 * D + sidx];
        } else {
            ring[0][1][widx] = U[(size_t)1 * D + sidx];
            ring[1][1][widx] = U[(size_t)2 * D + sidx];
            gstage = U[(size_t)3 * D + sidx];
        }
    }
    float vcur = v[r], vnext = v[(size_t)D + r], vn2 = v[(size_t)2 * D + r];

    // dec_0 is always mode 2 (first step: J_0 = v_0 k_0^T)
    float dwf = 0.f, dwi = 1.f;
    int dmode = 2;
    if (tid == 0) { decLDS[0][0] = 0.f; decLDS[0][1] = 1.f; decLDS[0][2] = 2.f; decLDS[0][3] = 0.f; }

    double SJ = 0.0, AJJ = 0.0, trSvv = 0.0;  // live on wave 0 only
    if (w == 0) {
        const double sl0 = (double)sl_arr[0];
        const double kq0 = (double)kqq_arr[0];
        const double vv0 = (double)vv_arr[0];
        trSvv = vv0;
        SJ  = sl0;
        AJJ = vv0 * kq0;
        if (lane == 0) {
            out[0] = (float)((0.5 * trSvv - SJ + 0.5 * AJJ) * invl_arr[0]);
            out[SEQ] = 1.f;
        }
    }
    __syncthreads();

    for (int i = 0; i < SEQ - 1; ++i) {
        const int p    = i % 3;
        const int pw   = (i + 2) % 3;
        const int par  = i & 1;
        const int parn = 1 - par;

        // ---- wave0: chain scalars (uniform s_loads, issued early) ----
        float c_sl = 0.f, c_kq = 0.f, c_vv = 0.f, c_kqa = 0.f, c_vva = 0.f,
              c_vvp = 0.f, c_kua = 0.f;
        double c_inv = 0.0;
        if (w == 0) {
            c_sl  = sl_arr[i + 1];  c_kq  = kqq_arr[i + 1]; c_vv  = vv_arr[i + 1];
            c_kqa = kq_adj[i + 1];  c_vva = vv_adj[i + 1];  c_vvp = vv_arr[i];
            c_kua = kU_adj[i + 1];  c_inv = invl_arr[i + 1];
        }

        // ---- k_i chunk: DIRECT global load (used post-barrier; ~600 cyc
        //      of dot+reduce+barrier cover its L2 latency) ----
        const float4* kg = (const float4*)(k + (size_t)i * D + cg * 16);
        const float4 kk0 = kg[0], kk1 = kg[1], kk2 = kg[2], kk3 = kg[3];

        // ---- ring reads: q_{i+1}, u_{i+1} (dot operands) ----
        const float4* q4 = (const float4*)&ring[p][0][c0s];
        const float4* u4 = (const float4*)&ring[p][1][c0s];
        const float4 qa = q4[0], qb = q4[1], qc = q4[2], qd = q4[3];
        const float4 ua = u4[0], ub = u4[1], uc = u4[2], ud = u4[3];

        // ---- dot: Y' = J_{i-1} q_{i+1}, W' = J_{i-1} u_{i+1} ----
        float pa = jr0.x * qa.x, pb = jr2.x * qc.x;
        pa = fmaf(jr0.y, qa.y, pa); pb = fmaf(jr2.y, qc.y, pb);
        pa = fmaf(jr0.z, qa.z, pa); pb = fmaf(jr2.z, qc.z, pb);
        pa = fmaf(jr0.w, qa.w, pa); pb = fmaf(jr2.w, qc.w, pb);
        pa = fmaf(jr1.x, qb.x, pa); pb = fmaf(jr3.x, qd.x, pb);
        pa = fmaf(jr1.y, qb.y, pa); pb = fmaf(jr3.y, qd.y, pb);
        pa = fmaf(jr1.z, qb.z, pa); pb = fmaf(jr3.z, qd.z, pb);
        pa = fmaf(jr1.w, qb.w, pa); pb = fmaf(jr3.w, qd.w, pb);
        float Yq = pa + pb;
        float va_ = jr0.x * ua.x, vb_ = jr2.x * uc.x;
        va_ = fmaf(jr0.y, ua.y, va_); vb_ = fmaf(jr2.y, uc.y, vb_);
        va_ = fmaf(jr0.z, ua.z, va_); vb_ = fmaf(jr2.z, uc.z, vb_);
        va_ = fmaf(jr0.w, ua.w, va_); vb_ = fmaf(jr2.w, uc.w, vb_);
        va_ = fmaf(jr1.x, ub.x, va_); vb_ = fmaf(jr3.x, ud.x, vb_);
        va_ = fmaf(jr1.y, ub.y, va_); vb_ = fmaf(jr3.y, ud.y, vb_);
        va_ = fmaf(jr1.z, ub.z, va_); vb_ = fmaf(jr3.z, ud.z, vb_);
        va_ = fmaf(jr1.w, ub.w, va_); vb_ = fmaf(jr3.w, ud.w, vb_);
        float Yw = va_ + vb_;

        // ---- reductions: combine partials first, then 3-level tails ----
        COMBINE8(Yq);              // full (Y')_r on all 8 lanes of row r
        COMBINE8(Yw);
        float z1 = vnext * Yq;     // all x8-counted -> *0.125 in fp64 chain
        float z2 = Yq * Yq;
        float z3 = vcur  * Yq;
        float z4 = vnext * Yw;
        TAIL3(z1);
        TAIL3(z2);
        TAIL3(z3);
        TAIL3(z4);
        if (lane == 63) *(float4*)&wred[par][w][0] = make_float4(z1, z2, z3, z4);

        // ---- staging write (phase i+2) + next prefetches (waves 6-9) ----
        if (stager) {
            ring[pw][which][widx] = gstage;
            const int tq = (i + 4 < SEQ) ? i + 4 : SEQ - 1;
            gstage = (which == 0) ? q[(size_t)tq * D + sidx]
                                  : U[(size_t)tq * D + sidx];
        }
        const int tv = (i + 3 < SEQ) ? i + 3 : SEQ - 1;
        const float vnew = v[(size_t)tv * D + r];

        __syncthreads();  // the ONE barrier

        if (w == 0) {
            // issue wred read first; J-update FMAs interleave with its latency
            float4 ww = *(const float4*)&wred[par][lane & 15][0];
            const float odwf = dwf, odwi = dwi;
            const int   odmode = dmode;
            UPDATE_J(odmode, odwf, odwi)

            REDUCE16(ww.x);
            REDUCE16(ww.y);
            REDUCE16(ww.z);
            REDUCE16(ww.w);

            double a, b;
            if (odmode == 2)      { a = 0.0; b = 1.0; }
            else if (odmode == 1) { a = (double)odwf; b = (double)odwi; }
            else                  { a = 1.0; b = 0.0; }
            const double kqa = (double)c_kqa, vva = (double)c_vva;
            const double vvp = (double)c_vvp, kua = (double)c_kua;
            const double r1 = (double)ww.x * 0.125, r2 = (double)ww.y * 0.125;
            const double r3 = (double)ww.z * 0.125, r4 = (double)ww.w * 0.125;
            const double Jqv  = a * r1 + b * (kqa * vva);
            const double Jq2  = a * a * r2 + 2.0 * a * b * kqa * r3 + b * b * kqa * kqa * vvp;
            const double AJl_ = a * r4 + b * kua * vva;

            trSvv += (double)c_vv;
            SJ    += Jqv;
            AJJ   += Jq2;
            const double s_l  = (double)c_sl;
            const double A_ll = (double)c_vv * (double)c_kq;
            const double AJJ_s  = (AJJ == 0.0)  ? 1.0 : AJJ;
            const double A_ll_s = (A_ll == 0.0) ? 1.0 : A_ll;
            const double denom   = AJJ * A_ll - AJl_ * AJl_;
            const double denom_s = (denom == 0.0) ? 1.0 : denom;
            const double rden = 1.0 / denom_s;
            const double wf = (A_ll * SJ - AJl_ * s_l) * rden;
            const double wi = (AJJ * s_l - AJl_ * SJ) * rden;
            double wf_c, wi_c;
            if (wi <= 0.0)      { wf_c = SJ / AJJ_s;  wi_c = 0.0; }
            else if (wf <= 0.0) { wf_c = 0.0;         wi_c = s_l / A_ll_s; }
            else                { wf_c = wf;          wi_c = wi; }
            const bool do_update = (s_l * AJJ_s - AJl_ * SJ) > 0.0;

            int mode;
            if (do_update) {
                mode = 1;
                const double nSJ = wf_c * SJ + wi_c * s_l;
                AJJ = wf_c * wf_c * AJJ + 2.0 * wf_c * wi_c * AJl_ + wi_c * wi_c * A_ll;
                SJ = nSJ;
            } else {
                mode = 0;
            }

            dwf = (float)wf_c; dwi = (float)wi_c; dmode = mode;
            if (lane == 0) {
                out[i + 1] = (float)((0.5 * trSvv - SJ + 0.5 * AJJ) * c_inv);
                out[SEQ + i + 1] = mode ? 1.f : 0.f;
                *(float4*)&decLDS[parn][0] = make_float4(dwf, dwi, (float)mode, 0.f);
            }
        } else {
            // dec_i written by wave0 in iter i-1 (post-B1(i-1)) -> separated
            // from this read by B1(i)
            const float4 df = *(const float4*)&decLDS[par][0];
            dwf = df.x; dwi = df.y; dmode = (int)df.z;
            UPDATE_J(dmode, dwf, dwi)
        }

        vcur = vnext; vnext = vn2; vn2 = vnew;
    }

    // ---- epilogue: apply final update (dec_{SEQ-1}) and store J ----
    __syncthreads();  // make wave0's decLDS[(SEQ-1)&1] write visible
    {
        const float4 df = *(const float4*)&decLDS[(SEQ - 1) & 1][0];
        const float fwf = df.x, fwi = df.y;
        const int   fmode = (int)df.z;
        const float4* kg = (const float4*)(k + (size_t)(SEQ - 1) * D + cg * 16);
        const float4 kk0 = kg[0], kk1 = kg[1], kk2 = kg[2], kk3 = kg[3];
        UPDATE_J(fmode, fwf, fwi)
        float* jbase = out + 2 * SEQ + (size_t)r * D + cg * 16;
        *(float4*)(jbase + 0)  = jr0;
        *(float4*)(jbase + 4)  = jr1;
        *(float4*)(jbase + 8)  = jr2;
        *(float4*)(jbase + 12) = jr3;
    }
}

extern "C" void kernel_launch(void* const* d_in, const int* in_sizes, int n_in,
                              void* d_out, int out_size, void* d_ws, size_t ws_size,
                              hipStream_t stream) {
    (void)in_sizes; (void)n_in; (void)out_size; (void)ws_size;
    const float* q = (const float*)d_in[0];
    const float* k = (const float*)d_in[1];
    const float* v = (const float*)d_in[2];
    float* out = (float*)d_out;

    float* U      = (float*)d_ws;            // SEQ*D floats (1 MB)
    float* sl     = U + (size_t)SEQ * D;     // SEQ
    float* kqq    = sl + SEQ;                // SEQ
    float* vv     = kqq + SEQ;               // SEQ
    float* kq_adj = vv + SEQ;                // SEQ
    float* vv_adj = kq_adj + SEQ;            // SEQ
    float* kU_adj = vv_adj + SEQ;            // SEQ
    double* invl  = (double*)(kU_adj + SEQ); // SEQ doubles (8B-aligned)

    precompute_kernel<<<SEQ, 256, 0, stream>>>(q, k, v, U, sl, kqq, vv,
                                               kq_adj, vv_adj, kU_adj, invl);
    scan_kernel<<<1, 1024, 0, stream>>>(q, k, v, U, sl, kqq, vv,
                                        kq_adj, vv_adj, kU_adj, invl, out);
}

// Round 14
// 2721.874 us; speedup vs baseline: 1.1789x; 1.1789x over previous
//
#include <hip/hip_runtime.h>

#define SEQ 2048
#define D 128

// ---------------------------------------------------------------------------
// Kernel 1: per-step J-independent quantities (fully parallel), UNNORMALIZED:
//   alpha_i  = k_s . q_i      (i <= s)
//   kqq[s]   = sum alpha_i^2          = l * (k^T Sqq_l k)
//   sl[s]    = sum alpha_i (v_s.v_i)  = l * (k^T Sqv_l v)
//   vv[s]    = v_s . v_s
//   U[s][c]  = sum_i q_i[c] alpha_i   = l * (Sqq_l k)[c]
//   invl[s]  = 1.0 / l   (fp64, for cost rescale)
// Adjacency scalars (for the scan's lagged-matvec corrections):
//   kq_adj[s] = k_{s-1} . q_s ; vv_adj[s] = v_s . v_{s-1} ; kU_adj[s] = k_{s-1} . U_s
// ---------------------------------------------------------------------------
__global__ __launch_bounds__(256) void precompute_kernel(
    const float* __restrict__ q, const float* __restrict__ k, const float* __restrict__ v,
    float* __restrict__ U, float* __restrict__ sl, float* __restrict__ kqq,
    float* __restrict__ vv, float* __restrict__ kq_adj, float* __restrict__ vv_adj,
    float* __restrict__ kU_adj, double* __restrict__ invl)
{
    const int s = blockIdx.x;
    const int tid = threadIdx.x;

    __shared__ float ks[D];
    __shared__ float vs[D];
    __shared__ float alpha[SEQ];
    __shared__ float red[8];
    __shared__ float upart[256];

    if (tid < D) ks[tid] = k[s * D + tid];
    else if (tid < 2 * D) vs[tid - D] = v[s * D + (tid - D)];
    __syncthreads();

    float p_a2 = 0.f, p_ab = 0.f;
    for (int i = tid; i <= s; i += 256) {
        const float4* qr = (const float4*)(q + (size_t)i * D);
        const float4* vr = (const float4*)(v + (size_t)i * D);
        float a = 0.f, b = 0.f;
#pragma unroll
        for (int j = 0; j < D / 4; ++j) {
            float4 q4 = qr[j];
            float4 v4 = vr[j];
            a += q4.x * ks[4 * j + 0] + q4.y * ks[4 * j + 1] + q4.z * ks[4 * j + 2] + q4.w * ks[4 * j + 3];
            b += v4.x * vs[4 * j + 0] + v4.y * vs[4 * j + 1] + v4.z * vs[4 * j + 2] + v4.w * vs[4 * j + 3];
        }
        alpha[i] = a;
        p_a2 += a * a;
        p_ab += a * b;
        if (i == s) vv[s] = b;  // v_s . v_s
    }
#pragma unroll
    for (int off = 1; off < 64; off <<= 1) {
        p_a2 += __shfl_xor(p_a2, off);
        p_ab += __shfl_xor(p_ab, off);
    }
    const int wid = tid >> 6;
    if ((tid & 63) == 0) { red[wid] = p_a2; red[4 + wid] = p_ab; }
    __syncthreads();  // also makes alpha[] visible to everyone
    if (tid == 0) {
        kqq[s] = red[0] + red[1] + red[2] + red[3];
        sl[s]  = red[4] + red[5] + red[6] + red[7];
        invl[s] = 1.0 / (double)(s + 1);
    }

    // ---- adjacency dots: wave 0 -> kq_adj[s+1], wave 1 -> vv_adj[s] ----
    if (tid < 64) {
        if (s + 1 < SEQ) {
            float p2 = ks[tid] * q[(size_t)(s + 1) * D + tid]
                     + ks[tid + 64] * q[(size_t)(s + 1) * D + 64 + tid];
#pragma unroll
            for (int off = 1; off < 64; off <<= 1) p2 += __shfl_xor(p2, off);
            if (tid == 0) kq_adj[s + 1] = p2;
        }
        if (s == 0 && tid == 0) { kq_adj[0] = 0.f; kU_adj[0] = 0.f; vv_adj[0] = 0.f; }
    } else if (tid < 128 && s > 0) {
        const int t2 = tid - 64;
        float p2 = vs[t2] * v[(size_t)(s - 1) * D + t2]
                 + vs[t2 + 64] * v[(size_t)(s - 1) * D + 64 + t2];
#pragma unroll
        for (int off = 1; off < 64; off <<= 1) p2 += __shfl_xor(p2, off);
        if (t2 == 0) vv_adj[s] = p2;
    }

    // pass 2: U[s][c] = sum_i q[i][c] * alpha[i], i parity-split over h,
    // 4 independent accumulators to break the dependent fma chain
    const int c = tid & (D - 1);
    const int h = tid >> 7;  // 0 or 1
    float a0 = 0.f, a1 = 0.f, a2 = 0.f, a3 = 0.f;
    int i = h;
    for (; i + 6 <= s; i += 8) {
        a0 = fmaf(q[(size_t)(i    ) * D + c], alpha[i    ], a0);
        a1 = fmaf(q[(size_t)(i + 2) * D + c], alpha[i + 2], a1);
        a2 = fmaf(q[(size_t)(i + 4) * D + c], alpha[i + 4], a2);
        a3 = fmaf(q[(size_t)(i + 6) * D + c], alpha[i + 6], a3);
    }
    for (; i <= s; i += 2) a0 = fmaf(q[(size_t)i * D + c], alpha[i], a0);
    upart[tid] = (a0 + a1) + (a2 + a3);
    __syncthreads();

    // U store + kU_adj[s] = k_{s-1}.U_s
    float kup = 0.f;
    if (tid < D) {
        const float uv = upart[tid] + upart[tid + D];
        U[(size_t)s * D + tid] = uv;
        if (s > 0) kup = uv * k[(size_t)(s - 1) * D + tid];
    }
#pragma unroll
    for (int off = 1; off < 64; off <<= 1) kup += __shfl_xor(kup, off);
    if (tid == 0)  red[0] = kup;
    if (tid == 64) red[1] = kup;
    __syncthreads();
    if (s > 0 && tid == 0) kU_adj[s] = red[0] + red[1];
}

// ---------------------------------------------------------------------------
// DPP helpers (R7/R10/R11-verified):
// ---------------------------------------------------------------------------
#define DPP_ADD(x, ctrl) \
    ((x) + __int_as_float(__builtin_amdgcn_update_dpp(0, __float_as_int(x), (ctrl), 0xf, 0xf, true)))
#define COMBINE8(x) do { x = DPP_ADD(x, 0xB1); x = DPP_ADD(x, 0x4E); x = DPP_ADD(x, 0x141); } while (0)
#define TAIL3(x)    do { x = DPP_ADD(x, 0x140); x = DPP_ADD(x, 0x142); x = DPP_ADD(x, 0x143); } while (0)
#define REDUCE16(x) do { x = DPP_ADD(x, 0xB1); x = DPP_ADD(x, 0x4E); x = DPP_ADD(x, 0x141); \
                         x = DPP_ADD(x, 0x140); } while (0)

#define UPDATE_J(MODE, WF, WI)                                                            \
    if ((MODE) == 2) {                                                                    \
        jr0.x = vcur*kk0.x; jr0.y = vcur*kk0.y; jr0.z = vcur*kk0.z; jr0.w = vcur*kk0.w;   \
        jr1.x = vcur*kk1.x; jr1.y = vcur*kk1.y; jr1.z = vcur*kk1.z; jr1.w = vcur*kk1.w;   \
        jr2.x = vcur*kk2.x; jr2.y = vcur*kk2.y; jr2.z = vcur*kk2.z; jr2.w = vcur*kk2.w;   \
        jr3.x = vcur*kk3.x; jr3.y = vcur*kk3.y; jr3.z = vcur*kk3.z; jr3.w = vcur*kk3.w;   \
    } else if ((MODE) == 1) {                                                             \
        const float wvr = (WI) * vcur;                                                    \
        jr0.x = fmaf(jr0.x, (WF), wvr*kk0.x); jr0.y = fmaf(jr0.y, (WF), wvr*kk0.y);       \
        jr0.z = fmaf(jr0.z, (WF), wvr*kk0.z); jr0.w = fmaf(jr0.w, (WF), wvr*kk0.w);       \
        jr1.x = fmaf(jr1.x, (WF), wvr*kk1.x); jr1.y = fmaf(jr1.y, (WF), wvr*kk1.y);       \
        jr1.z = fmaf(jr1.z, (WF), wvr*kk1.z); jr1.w = fmaf(jr1.w, (WF), wvr*kk1.w);       \
        jr2.x = fmaf(jr2.x, (WF), wvr*kk2.x); jr2.y = fmaf(jr2.y, (WF), wvr*kk2.y);       \
        jr2.z = fmaf(jr2.z, (WF), wvr*kk2.z); jr2.w = fmaf(jr2.w, (WF), wvr*kk2.w);       \
        jr3.x = fmaf(jr3.x, (WF), wvr*kk3.x); jr3.y = fmaf(jr3.y, (WF), wvr*kk3.y);       \
        jr3.z = fmaf(jr3.z, (WF), wvr*kk3.z); jr3.w = fmaf(jr3.w, (WF), wvr*kk3.w);       \
    }

// ---------------------------------------------------------------------------
// Kernel 2: sequential scan, 1024 threads (16 waves, 4/SIMD).
// ROUND-14 = R11 verbatim + global loads moved POST-barrier.
//   Drain theory: the HIP compiler emits `s_waitcnt vmcnt(0) lgkmcnt(0)`
//   before every s_barrier (m97/m131 evidence). R11 issued the stager
//   global load and vnew immediately PRE-barrier -> their full L2/HBM
//   latency lands on the barrier each iteration for all 16 waves. R12/R13
//   regressed precisely by adding more pre-barrier global loads. Fix: issue
//   all per-iteration global loads right AFTER the barrier, so the drain at
//   the NEXT barrier finds them complete (gap ~= 1 full iteration >> 900cyc).
//   Ring write also moves post-B1 (hazards: write post-B1(i) vs read
//   pre-B1(i+2) separated by B1(i+1); overwrite vs last read >= 2 barriers).
// Everything else identical to R11 (one barrier, parity wred/dec, swizzled
// ring incl. k, DPP reductions, wave0-exclusive fp64 chain).
// ---------------------------------------------------------------------------
__global__ __launch_bounds__(1024, 4) void scan_kernel(
    const float* __restrict__ q, const float* __restrict__ k, const float* __restrict__ v,
    const float* __restrict__ U, const float* __restrict__ sl_arr,
    const float* __restrict__ kqq_arr, const float* __restrict__ vv_arr,
    const float* __restrict__ kq_adj, const float* __restrict__ vv_adj,
    const float* __restrict__ kU_adj, const double* __restrict__ invl_arr,
    float* __restrict__ out)  // [0,2048) costs | [2048,4096) updated | [4096,...) J
{
    const int tid  = threadIdx.x;
    const int lane = tid & 63;
    const int w    = __builtin_amdgcn_readfirstlane(tid >> 6);  // 0..15
    const int r    = tid >> 3;        // my row 0..127
    const int cg   = tid & 7;
    const int c0s  = cg * 20;         // swizzled LDS chunk offset

    float4 jr0 = make_float4(0.f, 0.f, 0.f, 0.f);
    float4 jr1 = jr0, jr2 = jr0, jr3 = jr0;

    __shared__ float ring[3][3][160];                 // [phase][q,u,k][swizzled]
    __shared__ __align__(16) float wred[2][16][4];    // [parity][wave][r1,r2,r3,r4]
    __shared__ __align__(16) float decLDS[2][4];      // [parity][wf,wi,mode,-]

    // stagers: waves 6..11 (tid 384..767) — wave0 stays staging-free
    const bool stager = (tid >= 384) && (tid < 768);
    const int  which  = (tid >> 7) - 3;    // 0:q 1:u 2:k (when stager)
    const int  sidx   = tid & 127;
    const int  widx   = ((sidx >> 4) * 20) + (sidx & 15);  // swizzled write idx

    // ---- prologue: stage phases 0,1; gstage holds phase-2 data ----
    // invariant: phase j holds q_{j+1}, u_{j+1}, k_j
    float gstage = 0.f;
    if (stager) {
        if (which == 0) {
            ring[0][0][widx] = q[(size_t)1 * D + sidx];
            ring[1][0][widx] = q[(size_t)2 * D + sidx];
            gstage = q[(size_t)3 * D + sidx];
        } else if (which == 1) {
            ring[0][1][widx] = U[(size_t)1 * D + sidx];
            ring[1][1][widx] = U[(size_t)2 * D + sidx];
            gstage = U[(size_t)3 * D + sidx];
        } else {
            ring[0][2][widx] = k[sidx];
            ring[1][2][widx] = k[(size_t)1 * D + sidx];
            gstage = k[(size_t)2 * D + sidx];
        }
    }
    float vcur = v[r], vnext = v[(size_t)D + r], vn2 = v[(size_t)2 * D + r];

    // dec_0 is always mode 2 (first step: J_0 = v_0 k_0^T)
    float dwf = 0.f, dwi = 1.f;
    int dmode = 2;
    if (tid == 0) { decLDS[0][0] = 0.f; decLDS[0][1] = 1.f; decLDS[0][2] = 2.f; decLDS[0][3] = 0.f; }

    double SJ = 0.0, AJJ = 0.0, trSvv = 0.0;  // live on wave 0 only
    if (w == 0) {
        const double sl0 = (double)sl_arr[0];
        const double kq0 = (double)kqq_arr[0];
        const double vv0 = (double)vv_arr[0];
        trSvv = vv0;
        SJ  = sl0;
        AJJ = vv0 * kq0;
        if (lane == 0) {
            out[0] = (float)((0.5 * trSvv - SJ + 0.5 * AJJ) * invl_arr[0]);
            out[SEQ] = 1.f;
        }
    }
    __syncthreads();

    for (int i = 0; i < SEQ - 1; ++i) {
        const int p    = i % 3;
        const int pw   = (i + 2) % 3;
        const int par  = i & 1;
        const int parn = 1 - par;

        // ---- wave0: chain scalars (uniform s_loads, issued early) ----
        float c_sl = 0.f, c_kq = 0.f, c_vv = 0.f, c_kqa = 0.f, c_vva = 0.f,
              c_vvp = 0.f, c_kua = 0.f;
        double c_inv = 0.0;
        if (w == 0) {
            c_sl  = sl_arr[i + 1];  c_kq  = kqq_arr[i + 1]; c_vv  = vv_arr[i + 1];
            c_kqa = kq_adj[i + 1];  c_vva = vv_adj[i + 1];  c_vvp = vv_arr[i];
            c_kua = kU_adj[i + 1];  c_inv = invl_arr[i + 1];
        }

        // ---- ring reads: q_{i+1}, u_{i+1} (dot operands), k_i (update) ----
        const float4* q4 = (const float4*)&ring[p][0][c0s];
        const float4* u4 = (const float4*)&ring[p][1][c0s];
        const float4* k4 = (const float4*)&ring[p][2][c0s];
        const float4 qa = q4[0], qb = q4[1], qc = q4[2], qd = q4[3];
        const float4 ua = u4[0], ub = u4[1], uc = u4[2], ud = u4[3];
        const float4 kk0 = k4[0], kk1 = k4[1], kk2 = k4[2], kk3 = k4[3];

        // ---- dot: Y' = J_{i-1} q_{i+1}, W' = J_{i-1} u_{i+1} ----
        float pa = jr0.x * qa.x, pb = jr2.x * qc.x;
        pa = fmaf(jr0.y, qa.y, pa); pb = fmaf(jr2.y, qc.y, pb);
        pa = fmaf(jr0.z, qa.z, pa); pb = fmaf(jr2.z, qc.z, pb);
        pa = fmaf(jr0.w, qa.w, pa); pb = fmaf(jr2.w, qc.w, pb);
        pa = fmaf(jr1.x, qb.x, pa); pb = fmaf(jr3.x, qd.x, pb);
        pa = fmaf(jr1.y, qb.y, pa); pb = fmaf(jr3.y, qd.y, pb);
        pa = fmaf(jr1.z, qb.z, pa); pb = fmaf(jr3.z, qd.z, pb);
        pa = fmaf(jr1.w, qb.w, pa); pb = fmaf(jr3.w, qd.w, pb);
        float Yq = pa + pb;
        float va_ = jr0.x * ua.x, vb_ = jr2.x * uc.x;
        va_ = fmaf(jr0.y, ua.y, va_); vb_ = fmaf(jr2.y, uc.y, vb_);
        va_ = fmaf(jr0.z, ua.z, va_); vb_ = fmaf(jr2.z, uc.z, vb_);
        va_ = fmaf(jr0.w, ua.w, va_); vb_ = fmaf(jr2.w, uc.w, vb_);
        va_ = fmaf(jr1.x, ub.x, va_); vb_ = fmaf(jr3.x, ud.x, vb_);
        va_ = fmaf(jr1.y, ub.y, va_); vb_ = fmaf(jr3.y, ud.y, vb_);
        va_ = fmaf(jr1.z, ub.z, va_); vb_ = fmaf(jr3.z, ud.z, vb_);
        va_ = fmaf(jr1.w, ub.w, va_); vb_ = fmaf(jr3.w, ud.w, vb_);
        float Yw = va_ + vb_;

        // ---- reductions: combine partials first, then 3-level tails ----
        COMBINE8(Yq);              // full (Y')_r on all 8 lanes of row r
        COMBINE8(Yw);
        float z1 = vnext * Yq;     // all x8-counted -> *0.125 in fp64 chain
        float z2 = Yq * Yq;
        float z3 = vcur  * Yq;
        float z4 = vnext * Yw;
        TAIL3(z1);
        TAIL3(z2);
        TAIL3(z3);
        TAIL3(z4);
        if (lane == 63) *(float4*)&wred[par][w][0] = make_float4(z1, z2, z3, z4);

        __syncthreads();  // the ONE barrier (no fresh global loads in flight)

        // ---- staging write (gstage from last iter) + NEXT global loads,
        //      issued POST-barrier: the drain at B1(i+1) is ~1 full
        //      iteration away, so their latency never lands on a barrier ----
        if (stager) {
            ring[pw][which][widx] = gstage;
            const int tq = (i + 4 < SEQ) ? i + 4 : SEQ - 1;
            const int tk = (i + 3 < SEQ) ? i + 3 : SEQ - 1;
            gstage = (which == 0) ? q[(size_t)tq * D + sidx]
                   : (which == 1) ? U[(size_t)tq * D + sidx]
                                  : k[(size_t)tk * D + sidx];
        }
        const int tv = (i + 3 < SEQ) ? i + 3 : SEQ - 1;
        const float vnew = v[(size_t)tv * D + r];

        if (w == 0) {
            // issue wred read first; J-update FMAs interleave with its latency
            float4 ww = *(const float4*)&wred[par][lane & 15][0];
            const float odwf = dwf, odwi = dwi;
            const int   odmode = dmode;
            UPDATE_J(odmode, odwf, odwi)

            REDUCE16(ww.x);
            REDUCE16(ww.y);
            REDUCE16(ww.z);
            REDUCE16(ww.w);

            double a, b;
            if (odmode == 2)      { a = 0.0; b = 1.0; }
            else if (odmode == 1) { a = (double)odwf; b = (double)odwi; }
            else                  { a = 1.0; b = 0.0; }
            const double kqa = (double)c_kqa, vva = (double)c_vva;
            const double vvp = (double)c_vvp, kua = (double)c_kua;
            const double r1 = (double)ww.x * 0.125, r2 = (double)ww.y * 0.125;
            const double r3 = (double)ww.z * 0.125, r4 = (double)ww.w * 0.125;
            const double Jqv  = a * r1 + b * (kqa * vva);
            const double Jq2  = a * a * r2 + 2.0 * a * b * kqa * r3 + b * b * kqa * kqa * vvp;
            const double AJl_ = a * r4 + b * kua * vva;

            trSvv += (double)c_vv;
            SJ    += Jqv;
            AJJ   += Jq2;
            const double s_l  = (double)c_sl;
            const double A_ll = (double)c_vv * (double)c_kq;
            const double AJJ_s  = (AJJ == 0.0)  ? 1.0 : AJJ;
            const double A_ll_s = (A_ll == 0.0) ? 1.0 : A_ll;
            const double denom   = AJJ * A_ll - AJl_ * AJl_;
            const double denom_s = (denom == 0.0) ? 1.0 : denom;
            const double rden = 1.0 / denom_s;
            const double wf = (A_ll * SJ - AJl_ * s_l) * rden;
            const double wi = (AJJ * s_l - AJl_ * SJ) * rden;
            double wf_c, wi_c;
            if (wi <= 0.0)      { wf_c = SJ / AJJ_s;  wi_c = 0.0; }
            else if (wf <= 0.0) { wf_c = 0.0;         wi_c = s_l / A_ll_s; }
            else                { wf_c = wf;          wi_c = wi; }
            const bool do_update = (s_l * AJJ_s - AJl_ * SJ) > 0.0;

            int mode;
            if (do_update) {
                mode = 1;
                const double nSJ = wf_c * SJ + wi_c * s_l;
                AJJ = wf_c * wf_c * AJJ + 2.0 * wf_c * wi_c * AJl_ + wi_c * wi_c * A_ll;
                SJ = nSJ;
            } else {
                mode = 0;
            }

            dwf = (float)wf_c; dwi = (float)wi_c; dmode = mode;
            if (lane == 0) {
                out[i + 1] = (float)((0.5 * trSvv - SJ + 0.5 * AJJ) * c_inv);
                out[SEQ + i + 1] = mode ? 1.f : 0.f;
                *(float4*)&decLDS[parn][0] = make_float4(dwf, dwi, (float)mode, 0.f);
            }
        } else {
            // dec_i written by wave0 in iter i-1 (post-B1(i-1)) -> separated
            // from this read by B1(i)
            const float4 df = *(const float4*)&decLDS[par][0];
            dwf = df.x; dwi = df.y; dmode = (int)df.z;
            UPDATE_J(dmode, dwf, dwi)
        }

        vcur = vnext; vnext = vn2; vn2 = vnew;
    }

    // ---- epilogue: apply final update (dec_{SEQ-1}) and store J ----
    __syncthreads();  // make wave0's decLDS[(SEQ-1)&1] write visible
    {
        const float4 df = *(const float4*)&decLDS[(SEQ - 1) & 1][0];
        const float fwf = df.x, fwi = df.y;
        const int   fmode = (int)df.z;
        const int p = (SEQ - 1) % 3;
        const float4* k4 = (const float4*)&ring[p][2][c0s];
        const float4 kk0 = k4[0], kk1 = k4[1], kk2 = k4[2], kk3 = k4[3];
        UPDATE_J(fmode, fwf, fwi)
        float* jbase = out + 2 * SEQ + (size_t)r * D + cg * 16;
        *(float4*)(jbase + 0)  = jr0;
        *(float4*)(jbase + 4)  = jr1;
        *(float4*)(jbase + 8)  = jr2;
        *(float4*)(jbase + 12) = jr3;
    }
}

extern "C" void kernel_launch(void* const* d_in, const int* in_sizes, int n_in,
                              void* d_out, int out_size, void* d_ws, size_t ws_size,
                              hipStream_t stream) {
    (void)in_sizes; (void)n_in; (void)out_size; (void)ws_size;
    const float* q = (const float*)d_in[0];
    const float* k = (const float*)d_in[1];
    const float* v = (const float*)d_in[2];
    float* out = (float*)d_out;

    float* U      = (float*)d_ws;            // SEQ*D floats (1 MB)
    float* sl     = U + (size_t)SEQ * D;     // SEQ
    float* kqq    = sl + SEQ;                // SEQ
    float* vv     = kqq + SEQ;               // SEQ
    float* kq_adj = vv + SEQ;                // SEQ
    float* vv_adj = kq_adj + SEQ;            // SEQ
    float* kU_adj = vv_adj + SEQ;            // SEQ
    double* invl  = (double*)(kU_adj + SEQ); // SEQ doubles (8B-aligned)

    precompute_kernel<<<SEQ, 256, 0, stream>>>(q, k, v, U, sl, kqq, vv,
                                               kq_adj, vv_adj, kU_adj, invl);
    scan_kernel<<<1, 1024, 0, stream>>>(q, k, v, U, sl, kqq, vv,
                                        kq_adj, vv_adj, kU_adj, invl, out);
}

// Round 15
// 2412.023 us; speedup vs baseline: 1.3304x; 1.1285x over previous
//
#include <hip/hip_runtime.h>

#define SEQ 2048
#define D 128

typedef float v2f __attribute__((ext_vector_type(2)));
typedef float v4f __attribute__((ext_vector_type(4)));
#define LO2(v) __builtin_shufflevector(v, v, 0, 1)
#define HI2(v) __builtin_shufflevector(v, v, 2, 3)

// ---------------------------------------------------------------------------
// Kernel 1: per-step J-independent quantities (fully parallel), UNNORMALIZED:
//   alpha_i  = k_s . q_i      (i <= s)
//   kqq[s]   = sum alpha_i^2          = l * (k^T Sqq_l k)
//   sl[s]    = sum alpha_i (v_s.v_i)  = l * (k^T Sqv_l v)
//   vv[s]    = v_s . v_s
//   U[s][c]  = sum_i q_i[c] alpha_i   = l * (Sqq_l k)[c]
//   invl[s]  = 1.0 / l   (fp64, for cost rescale)
// Adjacency scalars (for the scan's lagged-matvec corrections):
//   kq_adj[s] = k_{s-1} . q_s ; vv_adj[s] = v_s . v_{s-1} ; kU_adj[s] = k_{s-1} . U_s
// ---------------------------------------------------------------------------
__global__ __launch_bounds__(256) void precompute_kernel(
    const float* __restrict__ q, const float* __restrict__ k, const float* __restrict__ v,
    float* __restrict__ U, float* __restrict__ sl, float* __restrict__ kqq,
    float* __restrict__ vv, float* __restrict__ kq_adj, float* __restrict__ vv_adj,
    float* __restrict__ kU_adj, double* __restrict__ invl)
{
    const int s = blockIdx.x;
    const int tid = threadIdx.x;

    __shared__ float ks[D];
    __shared__ float vs[D];
    __shared__ float alpha[SEQ];
    __shared__ float red[8];
    __shared__ float upart[256];

    if (tid < D) ks[tid] = k[s * D + tid];
    else if (tid < 2 * D) vs[tid - D] = v[s * D + (tid - D)];
    __syncthreads();

    float p_a2 = 0.f, p_ab = 0.f;
    for (int i = tid; i <= s; i += 256) {
        const float4* qr = (const float4*)(q + (size_t)i * D);
        const float4* vr = (const float4*)(v + (size_t)i * D);
        float a = 0.f, b = 0.f;
#pragma unroll
        for (int j = 0; j < D / 4; ++j) {
            float4 q4 = qr[j];
            float4 v4 = vr[j];
            a += q4.x * ks[4 * j + 0] + q4.y * ks[4 * j + 1] + q4.z * ks[4 * j + 2] + q4.w * ks[4 * j + 3];
            b += v4.x * vs[4 * j + 0] + v4.y * vs[4 * j + 1] + v4.z * vs[4 * j + 2] + v4.w * vs[4 * j + 3];
        }
        alpha[i] = a;
        p_a2 += a * a;
        p_ab += a * b;
        if (i == s) vv[s] = b;  // v_s . v_s
    }
#pragma unroll
    for (int off = 1; off < 64; off <<= 1) {
        p_a2 += __shfl_xor(p_a2, off);
        p_ab += __shfl_xor(p_ab, off);
    }
    const int wid = tid >> 6;
    if ((tid & 63) == 0) { red[wid] = p_a2; red[4 + wid] = p_ab; }
    __syncthreads();  // also makes alpha[] visible to everyone
    if (tid == 0) {
        kqq[s] = red[0] + red[1] + red[2] + red[3];
        sl[s]  = red[4] + red[5] + red[6] + red[7];
        invl[s] = 1.0 / (double)(s + 1);
    }

    // ---- adjacency dots: wave 0 -> kq_adj[s+1], wave 1 -> vv_adj[s] ----
    if (tid < 64) {
        if (s + 1 < SEQ) {
            float p2 = ks[tid] * q[(size_t)(s + 1) * D + tid]
                     + ks[tid + 64] * q[(size_t)(s + 1) * D + 64 + tid];
#pragma unroll
            for (int off = 1; off < 64; off <<= 1) p2 += __shfl_xor(p2, off);
            if (tid == 0) kq_adj[s + 1] = p2;
        }
        if (s == 0 && tid == 0) { kq_adj[0] = 0.f; kU_adj[0] = 0.f; vv_adj[0] = 0.f; }
    } else if (tid < 128 && s > 0) {
        const int t2 = tid - 64;
        float p2 = vs[t2] * v[(size_t)(s - 1) * D + t2]
                 + vs[t2 + 64] * v[(size_t)(s - 1) * D + 64 + t2];
#pragma unroll
        for (int off = 1; off < 64; off <<= 1) p2 += __shfl_xor(p2, off);
        if (t2 == 0) vv_adj[s] = p2;
    }

    // pass 2: U[s][c] = sum_i q[i][c] * alpha[i], i parity-split over h,
    // 4 independent accumulators to break the dependent fma chain
    const int c = tid & (D - 1);
    const int h = tid >> 7;  // 0 or 1
    float a0 = 0.f, a1 = 0.f, a2 = 0.f, a3 = 0.f;
    int i = h;
    for (; i + 6 <= s; i += 8) {
        a0 = fmaf(q[(size_t)(i    ) * D + c], alpha[i    ], a0);
        a1 = fmaf(q[(size_t)(i + 2) * D + c], alpha[i + 2], a1);
        a2 = fmaf(q[(size_t)(i + 4) * D + c], alpha[i + 4], a2);
        a3 = fmaf(q[(size_t)(i + 6) * D + c], alpha[i + 6], a3);
    }
    for (; i <= s; i += 2) a0 = fmaf(q[(size_t)i * D + c], alpha[i], a0);
    upart[tid] = (a0 + a1) + (a2 + a3);
    __syncthreads();

    // U store + kU_adj[s] = k_{s-1}.U_s
    float kup = 0.f;
    if (tid < D) {
        const float uv = upart[tid] + upart[tid + D];
        U[(size_t)s * D + tid] = uv;
        if (s > 0) kup = uv * k[(size_t)(s - 1) * D + tid];
    }
#pragma unroll
    for (int off = 1; off < 64; off <<= 1) kup += __shfl_xor(kup, off);
    if (tid == 0)  red[0] = kup;
    if (tid == 64) red[1] = kup;
    __syncthreads();
    if (s > 0 && tid == 0) kU_adj[s] = red[0] + red[1];
}

// ---------------------------------------------------------------------------
// DPP helpers (R7/R10/R11-verified):
// ---------------------------------------------------------------------------
#define DPP_ADD(x, ctrl) \
    ((x) + __int_as_float(__builtin_amdgcn_update_dpp(0, __float_as_int(x), (ctrl), 0xf, 0xf, true)))
#define COMBINE8(x) do { x = DPP_ADD(x, 0xB1); x = DPP_ADD(x, 0x4E); x = DPP_ADD(x, 0x141); } while (0)
#define TAIL3(x)    do { x = DPP_ADD(x, 0x140); x = DPP_ADD(x, 0x142); x = DPP_ADD(x, 0x143); } while (0)
#define REDUCE16(x) do { x = DPP_ADD(x, 0xB1); x = DPP_ADD(x, 0x4E); x = DPP_ADD(x, 0x141); \
                         x = DPP_ADD(x, 0x140); } while (0)

// packed-fp32 rank-1 update; uses j0..j7, k0_..k7_, vcur from enclosing scope
#define UPDATE_J(MODE, WF, WI)                                                \
    if ((MODE) == 2) {                                                        \
        const v2f vc2 = {vcur, vcur};                                         \
        j0 = vc2 * k0_; j1 = vc2 * k1_; j2 = vc2 * k2_; j3 = vc2 * k3_;       \
        j4 = vc2 * k4_; j5 = vc2 * k5_; j6 = vc2 * k6_; j7 = vc2 * k7_;       \
    } else if ((MODE) == 1) {                                                 \
        const v2f wf2 = {(WF), (WF)};                                         \
        const float wvr_ = (WI) * vcur;                                       \
        const v2f wv2 = {wvr_, wvr_};                                         \
        j0 = __builtin_elementwise_fma(j0, wf2, wv2 * k0_);                   \
        j1 = __builtin_elementwise_fma(j1, wf2, wv2 * k1_);                   \
        j2 = __builtin_elementwise_fma(j2, wf2, wv2 * k2_);                   \
        j3 = __builtin_elementwise_fma(j3, wf2, wv2 * k3_);                   \
        j4 = __builtin_elementwise_fma(j4, wf2, wv2 * k4_);                   \
        j5 = __builtin_elementwise_fma(j5, wf2, wv2 * k5_);                   \
        j6 = __builtin_elementwise_fma(j6, wf2, wv2 * k6_);                   \
        j7 = __builtin_elementwise_fma(j7, wf2, wv2 * k7_);                   \
    }

// ---------------------------------------------------------------------------
// Kernel 2: sequential scan, 1024 threads (16 waves, 4/SIMD).
// ROUND-15 = R14 skeleton (proven: one barrier, post-barrier global loads,
// DPP reductions, wave0-exclusive fp64 chain) + VALU instruction cuts:
//  (1) packed fp32 (v_pk_fma_f32 via float2 ext-vectors): dot 32->16 instr,
//      rank-1 update 16->8 — the CU is 78% VALU-issue-bound (R14 VALUBusy
//      0.306% ~= 78% of the 1-of-256-CU ceiling 0.391%).
//  (2) loop unrolled x3 with COMPILE-TIME ring phases; wred/dec now
//      3-deep phase-indexed (same hazard separation as parity-2: write at
//      body I+3 vs read at body I straddles 2+ barriers).
// ---------------------------------------------------------------------------
__global__ __launch_bounds__(1024, 4) void scan_kernel(
    const float* __restrict__ q, const float* __restrict__ k, const float* __restrict__ v,
    const float* __restrict__ U, const float* __restrict__ sl_arr,
    const float* __restrict__ kqq_arr, const float* __restrict__ vv_arr,
    const float* __restrict__ kq_adj, const float* __restrict__ vv_adj,
    const float* __restrict__ kU_adj, const double* __restrict__ invl_arr,
    float* __restrict__ out)  // [0,2048) costs | [2048,4096) updated | [4096,...) J
{
    const int tid  = threadIdx.x;
    const int lane = tid & 63;
    const int w    = __builtin_amdgcn_readfirstlane(tid >> 6);  // 0..15
    const int r    = tid >> 3;        // my row 0..127
    const int cg   = tid & 7;
    const int c0s  = cg * 20;         // swizzled LDS chunk offset

    v2f j0 = {0.f, 0.f}, j1 = j0, j2 = j0, j3 = j0, j4 = j0, j5 = j0, j6 = j0, j7 = j0;

    __shared__ float ring[3][3][160];                 // [phase][q,u,k][swizzled]
    __shared__ __align__(16) float wred[3][16][4];    // [phase][wave][r1,r2,r3,r4]
    __shared__ __align__(16) float decLDS[3][4];      // [phase][wf,wi,mode,-]

    // stagers: waves 6..11 (tid 384..767) — wave0 stays staging-free
    const bool stager = (tid >= 384) && (tid < 768);
    const int  which  = (tid >> 7) - 3;    // 0:q 1:u 2:k (when stager)
    const int  sidx   = tid & 127;
    const int  widx   = ((sidx >> 4) * 20) + (sidx & 15);  // swizzled write idx

    // ---- prologue: stage phases 0,1; gstage holds phase-2 data ----
    // invariant: phase j holds q_{j+1}, u_{j+1}, k_j
    float gstage = 0.f;
    if (stager) {
        if (which == 0) {
            ring[0][0][widx] = q[(size_t)1 * D + sidx];
            ring[1][0][widx] = q[(size_t)2 * D + sidx];
            gstage = q[(size_t)3 * D + sidx];
        } else if (which == 1) {
            ring[0][1][widx] = U[(size_t)1 * D + sidx];
            ring[1][1][widx] = U[(size_t)2 * D + sidx];
            gstage = U[(size_t)3 * D + sidx];
        } else {
            ring[0][2][widx] = k[sidx];
            ring[1][2][widx] = k[(size_t)1 * D + sidx];
            gstage = k[(size_t)2 * D + sidx];
        }
    }
    float vcur = v[r], vnext = v[(size_t)D + r], vn2 = v[(size_t)2 * D + r];

    // dec_0 is always mode 2 (first step: J_0 = v_0 k_0^T); read at body 0 (phase 0)
    float dwf = 0.f, dwi = 1.f;
    int dmode = 2;
    if (tid == 0) { decLDS[0][0] = 0.f; decLDS[0][1] = 1.f; decLDS[0][2] = 2.f; decLDS[0][3] = 0.f; }

    double SJ = 0.0, AJJ = 0.0, trSvv = 0.0;  // live on wave 0 only
    if (w == 0) {
        const double sl0 = (double)sl_arr[0];
        const double kq0 = (double)kqq_arr[0];
        const double vv0 = (double)vv_arr[0];
        trSvv = vv0;
        SJ  = sl0;
        AJJ = vv0 * kq0;
        if (lane == 0) {
            out[0] = (float)((0.5 * trSvv - SJ + 0.5 * AJJ) * invl_arr[0]);
            out[SEQ] = 1.f;
        }
    }
    __syncthreads();

#define STEP_BODY(I, P, PN, PW)                                               \
{                                                                             \
    float c_sl = 0.f, c_kq = 0.f, c_vv = 0.f, c_kqa = 0.f, c_vva = 0.f,       \
          c_vvp = 0.f, c_kua = 0.f;                                           \
    double c_inv = 0.0;                                                       \
    if (w == 0) {                                                             \
        c_sl  = sl_arr[(I) + 1];  c_kq  = kqq_arr[(I) + 1];                   \
        c_vv  = vv_arr[(I) + 1];  c_kqa = kq_adj[(I) + 1];                    \
        c_vva = vv_adj[(I) + 1];  c_vvp = vv_arr[(I)];                        \
        c_kua = kU_adj[(I) + 1];  c_inv = invl_arr[(I) + 1];                  \
    }                                                                         \
    const v4f Qa = ((const v4f*)&ring[P][0][c0s])[0];                         \
    const v4f Qb = ((const v4f*)&ring[P][0][c0s])[1];                         \
    const v4f Qc = ((const v4f*)&ring[P][0][c0s])[2];                         \
    const v4f Qd = ((const v4f*)&ring[P][0][c0s])[3];                         \
    const v4f Ua = ((const v4f*)&ring[P][1][c0s])[0];                         \
    const v4f Ub = ((const v4f*)&ring[P][1][c0s])[1];                         \
    const v4f Uc = ((const v4f*)&ring[P][1][c0s])[2];                         \
    const v4f Ud = ((const v4f*)&ring[P][1][c0s])[3];                         \
    const v4f Ka = ((const v4f*)&ring[P][2][c0s])[0];                         \
    const v4f Kb = ((const v4f*)&ring[P][2][c0s])[1];                         \
    const v4f Kc = ((const v4f*)&ring[P][2][c0s])[2];                         \
    const v4f Kd = ((const v4f*)&ring[P][2][c0s])[3];                         \
    const v2f k0_ = LO2(Ka), k1_ = HI2(Ka), k2_ = LO2(Kb), k3_ = HI2(Kb);     \
    const v2f k4_ = LO2(Kc), k5_ = HI2(Kc), k6_ = LO2(Kd), k7_ = HI2(Kd);     \
    v2f aq0 = {0.f, 0.f}, aq1 = aq0, aq2 = aq0, aq3 = aq0;                    \
    aq0 = __builtin_elementwise_fma(j0, LO2(Qa), aq0);                        \
    aq1 = __builtin_elementwise_fma(j1, HI2(Qa), aq1);                        \
    aq2 = __builtin_elementwise_fma(j2, LO2(Qb), aq2);                        \
    aq3 = __builtin_elementwise_fma(j3, HI2(Qb), aq3);                        \
    aq0 = __builtin_elementwise_fma(j4, LO2(Qc), aq0);                        \
    aq1 = __builtin_elementwise_fma(j5, HI2(Qc), aq1);                        \
    aq2 = __builtin_elementwise_fma(j6, LO2(Qd), aq2);                        \
    aq3 = __builtin_elementwise_fma(j7, HI2(Qd), aq3);                        \
    const v2f sq_ = (aq0 + aq1) + (aq2 + aq3);                                \
    float Yq = sq_.x + sq_.y;                                                 \
    v2f au0 = {0.f, 0.f}, au1 = au0, au2 = au0, au3 = au0;                    \
    au0 = __builtin_elementwise_fma(j0, LO2(Ua), au0);                        \
    au1 = __builtin_elementwise_fma(j1, HI2(Ua), au1);                        \
    au2 = __builtin_elementwise_fma(j2, LO2(Ub), au2);                        \
    au3 = __builtin_elementwise_fma(j3, HI2(Ub), au3);                        \
    au0 = __builtin_elementwise_fma(j4, LO2(Uc), au0);                        \
    au1 = __builtin_elementwise_fma(j5, HI2(Uc), au1);                        \
    au2 = __builtin_elementwise_fma(j6, LO2(Ud), au2);                        \
    au3 = __builtin_elementwise_fma(j7, HI2(Ud), au3);                        \
    const v2f su_ = (au0 + au1) + (au2 + au3);                                \
    float Yw = su_.x + su_.y;                                                 \
    COMBINE8(Yq);                                                             \
    COMBINE8(Yw);                                                             \
    float z1 = vnext * Yq;                                                    \
    float z2 = Yq * Yq;                                                       \
    float z3 = vcur  * Yq;                                                    \
    float z4 = vnext * Yw;                                                    \
    TAIL3(z1);                                                                \
    TAIL3(z2);                                                                \
    TAIL3(z3);                                                                \
    TAIL3(z4);                                                                \
    if (lane == 63) *(float4*)&wred[P][w][0] = make_float4(z1, z2, z3, z4);   \
    __syncthreads();                                                          \
    if (stager) {                                                             \
        ring[PW][which][widx] = gstage;                                       \
        const int tq_ = ((I) + 4 < SEQ) ? (I) + 4 : SEQ - 1;                  \
        const int tk_ = ((I) + 3 < SEQ) ? (I) + 3 : SEQ - 1;                  \
        gstage = (which == 0) ? q[(size_t)tq_ * D + sidx]                     \
               : (which == 1) ? U[(size_t)tq_ * D + sidx]                     \
                              : k[(size_t)tk_ * D + sidx];                    \
    }                                                                         \
    const int tv_ = ((I) + 3 < SEQ) ? (I) + 3 : SEQ - 1;                      \
    const float vnew_ = v[(size_t)tv_ * D + r];                               \
    if (w == 0) {                                                             \
        float4 ww = *(const float4*)&wred[P][lane & 15][0];                   \
        const float odwf = dwf, odwi = dwi;                                   \
        const int   odmode = dmode;                                           \
        UPDATE_J(odmode, odwf, odwi)                                          \
        REDUCE16(ww.x);                                                       \
        REDUCE16(ww.y);                                                       \
        REDUCE16(ww.z);                                                       \
        REDUCE16(ww.w);                                                       \
        double a_, b_;                                                        \
        if (odmode == 2)      { a_ = 0.0; b_ = 1.0; }                         \
        else if (odmode == 1) { a_ = (double)odwf; b_ = (double)odwi; }       \
        else                  { a_ = 1.0; b_ = 0.0; }                         \
        const double kqa = (double)c_kqa, vva = (double)c_vva;                \
        const double vvp = (double)c_vvp, kua = (double)c_kua;                \
        const double r1 = (double)ww.x * 0.125, r2 = (double)ww.y * 0.125;    \
        const double r3 = (double)ww.z * 0.125, r4 = (double)ww.w * 0.125;    \
        const double Jqv  = a_ * r1 + b_ * (kqa * vva);                       \
        const double Jq2  = a_ * a_ * r2 + 2.0 * a_ * b_ * kqa * r3          \
                          + b_ * b_ * kqa * kqa * vvp;                        \
        const double AJl_ = a_ * r4 + b_ * kua * vva;                         \
        trSvv += (double)c_vv;                                                \
        SJ    += Jqv;                                                         \
        AJJ   += Jq2;                                                         \
        const double s_l  = (double)c_sl;                                     \
        const double A_ll = (double)c_vv * (double)c_kq;                      \
        const double AJJ_s  = (AJJ == 0.0)  ? 1.0 : AJJ;                      \
        const double A_ll_s = (A_ll == 0.0) ? 1.0 : A_ll;                     \
        const double denom   = AJJ * A_ll - AJl_ * AJl_;                      \
        const double denom_s = (denom == 0.0) ? 1.0 : denom;                  \
        const double rden = 1.0 / denom_s;                                    \
        const double wf = (A_ll * SJ - AJl_ * s_l) * rden;                    \
        const double wi = (AJJ * s_l - AJl_ * SJ) * rden;                     \
        double wf_c, wi_c;                                                    \
        if (wi <= 0.0)      { wf_c = SJ / AJJ_s;  wi_c = 0.0; }               \
        else if (wf <= 0.0) { wf_c = 0.0;         wi_c = s_l / A_ll_s; }      \
        else                { wf_c = wf;          wi_c = wi; }                \
        const bool do_update = (s_l * AJJ_s - AJl_ * SJ) > 0.0;               \
        int mode;                                                             \
        if (do_update) {                                                      \
            mode = 1;                                                         \
            const double nSJ = wf_c * SJ + wi_c * s_l;                        \
            AJJ = wf_c * wf_c * AJJ + 2.0 * wf_c * wi_c * AJl_                \
                + wi_c * wi_c * A_ll;                                         \
            SJ = nSJ;                                                         \
        } else {                                                              \
            mode = 0;                                                         \
        }                                                                     \
        dwf = (float)wf_c; dwi = (float)wi_c; dmode = mode;                   \
        if (lane == 0) {                                                      \
            out[(I) + 1] = (float)((0.5 * trSvv - SJ + 0.5 * AJJ) * c_inv);   \
            out[SEQ + (I) + 1] = mode ? 1.f : 0.f;                            \
            *(float4*)&decLDS[PN][0] = make_float4(dwf, dwi, (float)mode, 0.f);\
        }                                                                     \
    } else {                                                                  \
        const float4 df = *(const float4*)&decLDS[P][0];                      \
        dwf = df.x; dwi = df.y; dmode = (int)df.z;                            \
        UPDATE_J(dmode, dwf, dwi)                                             \
    }                                                                         \
    vcur = vnext; vnext = vn2; vn2 = vnew_;                                   \
}

    // bodies I = 0..SEQ-2 (2047 of them): 682 x3-unrolled + 1 tail (2046%3==0)
    for (int i = 0; i + 2 < SEQ - 1; i += 3) {
        STEP_BODY(i,     0, 1, 2)
        STEP_BODY(i + 1, 1, 2, 0)
        STEP_BODY(i + 2, 2, 0, 1)
    }
    STEP_BODY(SEQ - 2, 0, 1, 2)
#undef STEP_BODY

    // ---- epilogue: apply final update (dec_{SEQ-1}, phase (SEQ-1)%3 = 1) ----
    __syncthreads();  // make wave0's decLDS[1] write visible
    {
        const float4 df = *(const float4*)&decLDS[1][0];
        const float fwf = df.x, fwi = df.y;
        const int   fmode = (int)df.z;
        const v4f Ka = ((const v4f*)&ring[1][2][c0s])[0];
        const v4f Kb = ((const v4f*)&ring[1][2][c0s])[1];
        const v4f Kc = ((const v4f*)&ring[1][2][c0s])[2];
        const v4f Kd = ((const v4f*)&ring[1][2][c0s])[3];
        const v2f k0_ = LO2(Ka), k1_ = HI2(Ka), k2_ = LO2(Kb), k3_ = HI2(Kb);
        const v2f k4_ = LO2(Kc), k5_ = HI2(Kc), k6_ = LO2(Kd), k7_ = HI2(Kd);
        UPDATE_J(fmode, fwf, fwi)
        float* jbase = out + 2 * SEQ + (size_t)r * D + cg * 16;
        *(v4f*)(jbase + 0)  = __builtin_shufflevector(j0, j1, 0, 1, 2, 3);
        *(v4f*)(jbase + 4)  = __builtin_shufflevector(j2, j3, 0, 1, 2, 3);
        *(v4f*)(jbase + 8)  = __builtin_shufflevector(j4, j5, 0, 1, 2, 3);
        *(v4f*)(jbase + 12) = __builtin_shufflevector(j6, j7, 0, 1, 2, 3);
    }
}

extern "C" void kernel_launch(void* const* d_in, const int* in_sizes, int n_in,
                              void* d_out, int out_size, void* d_ws, size_t ws_size,
                              hipStream_t stream) {
    (void)in_sizes; (void)n_in; (void)out_size; (void)ws_size;
    const float* q = (const float*)d_in[0];
    const float* k = (const float*)d_in[1];
    const float* v = (const float*)d_in[2];
    float* out = (float*)d_out;

    float* U      = (float*)d_ws;            // SEQ*D floats (1 MB)
    float* sl     = U + (size_t)SEQ * D;     // SEQ
    float* kqq    = sl + SEQ;                // SEQ
    float* vv     = kqq + SEQ;               // SEQ
    float* kq_adj = vv + SEQ;                // SEQ
    float* vv_adj = kq_adj + SEQ;            // SEQ
    float* kU_adj = vv_adj + SEQ;            // SEQ
    double* invl  = (double*)(kU_adj + SEQ); // SEQ doubles (8B-aligned)

    precompute_kernel<<<SEQ, 256, 0, stream>>>(q, k, v, U, sl, kqq, vv,
                                               kq_adj, vv_adj, kU_adj, invl);
    scan_kernel<<<1, 1024, 0, stream>>>(q, k, v, U, sl, kqq, vv,
                                        kq_adj, vv_adj, kU_adj, invl, out);
}